// Round 1
// baseline (82.873 us; speedup 1.0000x reference)
//
#include <hip/hip_runtime.h>

// YOLOv1 loss: pre/lab [32768, 30, 7, 7] fp32 -> scalar (sum / B).
// Memory-bound streaming reduction (~385 MB). One cell per thread-iteration;
// per-channel offsets are compile-time immediates so loads coalesce into
// contiguous runs per wave. Deterministic 2-pass reduction via d_ws.

#define BATCH 32768
#define S2    49      // 7*7 cells per batch
#define CST   1470    // 30*49 floats per batch per tensor
#define NCELL (BATCH * S2)

__device__ __forceinline__ float iou4(float px1, float py1, float px2, float py2,
                                      float lx1, float ly1, float lx2, float ly2) {
    float ix1 = fmaxf(px1, lx1), iy1 = fmaxf(py1, ly1);
    float ix2 = fminf(px2, lx2), iy2 = fminf(py2, ly2);
    float iw = fmaxf(ix2 - ix1 + 1.0f, 0.0f);
    float ih = fmaxf(iy2 - iy1 + 1.0f, 0.0f);
    float inter = iw * ih;
    float a1 = (px2 - px1 + 1.0f) * (py2 - py1 + 1.0f);
    float a2 = (lx2 - lx1 + 1.0f) * (ly2 - ly1 + 1.0f);
    return inter / (a1 + a2 - inter);
}

__global__ __launch_bounds__(256) void yolo_loss_main(const float* __restrict__ pre,
                                                      const float* __restrict__ lab,
                                                      float* __restrict__ partials) {
    float acc = 0.0f;
    const int stride = gridDim.x * blockDim.x;
    for (int cell = blockIdx.x * blockDim.x + threadIdx.x; cell < NCELL; cell += stride) {
        int b = cell / S2;
        int s = cell - b * S2;
        const float* __restrict__ P = pre + b * CST + s;
        const float* __restrict__ L = lab + b * CST + s;

        float p0 = P[0],      p1 = P[S2],     p2 = P[2 * S2], p3 = P[3 * S2], p4 = P[4 * S2];
        float p5 = P[5 * S2], p6 = P[6 * S2], p7 = P[7 * S2], p8 = P[8 * S2], p9 = P[9 * S2];
        float l0 = L[0],      l1 = L[S2],     l2 = L[2 * S2], l3 = L[3 * S2], l4 = L[4 * S2];
        float l5 = L[5 * S2], l6 = L[6 * S2], l7 = L[7 * S2], l8 = L[8 * S2];
        // lab channel 9 is unused by the reference -> never loaded.

        float iou1 = iou4(p0, p1, p2, p3, l0, l1, l2, l3);
        float iou2 = iou4(p5, p6, p7, p8, l5, l6, l7, l8);
        bool resp1 = iou1 >= iou2;

        float d0 = l0 - p0, d1 = l1 - p1, d5 = l5 - p5, d6 = l6 - p6;
        float addr1 = 5.0f * (d0 * d0 + d1 * d1);
        float addr2 = 5.0f * (d5 * d5 + d6 * d6);

        float e2 = sqrtf(p2) - sqrtf(l2), e3 = sqrtf(p3) - sqrtf(l3);
        float e7 = sqrtf(p7) - sqrtf(l7), e8 = sqrtf(p8) - sqrtf(l8);
        float size1 = 5.0f * (e2 * e2 + e3 * e3);
        float size2 = 5.0f * (e7 * e7 + e8 * e8);

        float du = p9 - (resp1 ? iou1 : iou2);
        float conf = 0.5f * du * du;

        float obj_terms = (resp1 ? (addr1 + size1) : (addr2 + size2)) + conf;
        float pn = p4 + p9;
        float noobj = 0.5f * pn * pn;
        float cellv = (l4 == 1.0f) ? obj_terms : noobj;

        float cls = 0.0f;
        #pragma unroll
        for (int c = 10; c < 30; ++c) {
            float d = P[c * S2] - L[c * S2];
            cls += d * d;
        }
        acc += cellv + cls;
    }

    // wave (64-lane) butterfly reduce
    #pragma unroll
    for (int off = 32; off > 0; off >>= 1) acc += __shfl_down(acc, off);

    __shared__ float red[4];
    int lane = threadIdx.x & 63, wid = threadIdx.x >> 6;
    if (lane == 0) red[wid] = acc;
    __syncthreads();
    if (threadIdx.x == 0) partials[blockIdx.x] = red[0] + red[1] + red[2] + red[3];
}

__global__ __launch_bounds__(256) void yolo_loss_final(const float* __restrict__ partials,
                                                       int n, float* __restrict__ out) {
    double v = 0.0;
    for (int i = (int)threadIdx.x; i < n; i += 256) v += (double)partials[i];
    __shared__ double sm[256];
    sm[threadIdx.x] = v;
    __syncthreads();
    for (int s = 128; s > 0; s >>= 1) {
        if ((int)threadIdx.x < s) sm[threadIdx.x] += sm[threadIdx.x + s];
        __syncthreads();
    }
    if (threadIdx.x == 0) out[0] = (float)(sm[0] * (1.0 / (double)BATCH));
}

extern "C" void kernel_launch(void* const* d_in, const int* in_sizes, int n_in,
                              void* d_out, int out_size, void* d_ws, size_t ws_size,
                              hipStream_t stream) {
    const float* pre = (const float*)d_in[0];
    const float* lab = (const float*)d_in[1];
    float* out = (float*)d_out;
    float* partials = (float*)d_ws;

    int nblk = 2048;
    if (ws_size < (size_t)nblk * sizeof(float)) {
        nblk = (int)(ws_size / sizeof(float));
        if (nblk < 1) nblk = 1;
    }

    yolo_loss_main<<<nblk, 256, 0, stream>>>(pre, lab, partials);
    yolo_loss_final<<<1, 256, 0, stream>>>(partials, nblk, out);
}

// Round 2
// 73.014 us; speedup vs baseline: 1.1350x; 1.1350x over previous
//
#include <hip/hip_runtime.h>

// YOLOv1 loss: pre/lab [32768, 30, 7, 7] fp32 -> scalar (sum / B).
// Round 2: round-1 kernel was VMEM-issue bound (94.7M scalar dword loads,
// ~1.2 VMEM inst/cyc/CU, 25% HBM BW). Now stage contiguous float4 runs
// (2 batches = 735 float4 per tensor) into LDS, compute cells from LDS.
// VMEM inst count drops 4x -> BW-bound.

#define BATCH   32768
#define S2      49            // 7*7 cells per batch
#define CPB     1470          // floats per batch per tensor (30*49)
#define NB      2             // batches per group
#define GFLOATS (NB * CPB)    // 2940 floats per group per tensor
#define GVEC    (GFLOATS / 4) // 735 float4 (16B-aligned: 2940 % 4 == 0)
#define NGROUPS (BATCH / NB)  // 16384
#define CELLS   (NB * S2)     // 98 cells per group
#define NBLK    1536          // 6 blocks/CU * 256 CUs

__device__ __forceinline__ float iou4(float px1, float py1, float px2, float py2,
                                      float lx1, float ly1, float lx2, float ly2) {
    float ix1 = fmaxf(px1, lx1), iy1 = fmaxf(py1, ly1);
    float ix2 = fminf(px2, lx2), iy2 = fminf(py2, ly2);
    float iw = fmaxf(ix2 - ix1 + 1.0f, 0.0f);
    float ih = fmaxf(iy2 - iy1 + 1.0f, 0.0f);
    float inter = iw * ih;
    float a1 = (px2 - px1 + 1.0f) * (py2 - py1 + 1.0f);
    float a2 = (lx2 - lx1 + 1.0f) * (ly2 - ly1 + 1.0f);
    return inter / (a1 + a2 - inter);
}

__global__ __launch_bounds__(256) void yolo_loss_main(const float4* __restrict__ pre4,
                                                      const float4* __restrict__ lab4,
                                                      float* __restrict__ partials) {
    __shared__ float4 smem[2 * GVEC];   // 23520 B: [0,GVEC)=pre, [GVEC,2*GVEC)=lab
    __shared__ float red[4];
    float* preS = (float*)smem;
    float* labS = (float*)(smem + GVEC);
    const int tid = threadIdx.x;

    float acc = 0.0f;
    for (int g = blockIdx.x; g < NGROUPS; g += gridDim.x) {
        const float4* __restrict__ ps = pre4 + (size_t)g * GVEC;
        const float4* __restrict__ ls = lab4 + (size_t)g * GVEC;
        #pragma unroll
        for (int k = 0; k < 3; ++k) {               // ceil(735/256) = 3
            int i = tid + k * 256;
            if (i < GVEC) {
                smem[i]        = ps[i];
                smem[GVEC + i] = ls[i];
            }
        }
        __syncthreads();

        if (tid < CELLS) {
            int bl = tid / S2;
            int s  = tid - bl * S2;
            const float* __restrict__ P = preS + bl * CPB + s;
            const float* __restrict__ L = labS + bl * CPB + s;

            float p0 = P[0],      p1 = P[S2],     p2 = P[2 * S2], p3 = P[3 * S2], p4 = P[4 * S2];
            float p5 = P[5 * S2], p6 = P[6 * S2], p7 = P[7 * S2], p8 = P[8 * S2], p9 = P[9 * S2];
            float l0 = L[0],      l1 = L[S2],     l2 = L[2 * S2], l3 = L[3 * S2], l4 = L[4 * S2];
            float l5 = L[5 * S2], l6 = L[6 * S2], l7 = L[7 * S2], l8 = L[8 * S2];

            float iou1 = iou4(p0, p1, p2, p3, l0, l1, l2, l3);
            float iou2 = iou4(p5, p6, p7, p8, l5, l6, l7, l8);
            bool resp1 = iou1 >= iou2;

            float d0 = l0 - p0, d1 = l1 - p1, d5 = l5 - p5, d6 = l6 - p6;
            float addr1 = 5.0f * (d0 * d0 + d1 * d1);
            float addr2 = 5.0f * (d5 * d5 + d6 * d6);

            float e2 = sqrtf(p2) - sqrtf(l2), e3 = sqrtf(p3) - sqrtf(l3);
            float e7 = sqrtf(p7) - sqrtf(l7), e8 = sqrtf(p8) - sqrtf(l8);
            float size1 = 5.0f * (e2 * e2 + e3 * e3);
            float size2 = 5.0f * (e7 * e7 + e8 * e8);

            float du = p9 - (resp1 ? iou1 : iou2);
            float conf = 0.5f * du * du;

            float obj_terms = (resp1 ? (addr1 + size1) : (addr2 + size2)) + conf;
            float pn = p4 + p9;
            float noobj = 0.5f * pn * pn;
            float cellv = (l4 == 1.0f) ? obj_terms : noobj;

            float cls = 0.0f;
            #pragma unroll
            for (int c = 10; c < 30; ++c) {
                float d = P[c * S2] - L[c * S2];
                cls += d * d;
            }
            acc += cellv + cls;
        }
        __syncthreads();
    }

    // wave butterfly reduce, then cross-wave via LDS (deterministic)
    #pragma unroll
    for (int off = 32; off > 0; off >>= 1) acc += __shfl_down(acc, off);
    int lane = tid & 63, wid = tid >> 6;
    if (lane == 0) red[wid] = acc;
    __syncthreads();
    if (tid == 0) partials[blockIdx.x] = red[0] + red[1] + red[2] + red[3];
}

__global__ __launch_bounds__(256) void yolo_loss_final(const float* __restrict__ partials,
                                                       int n, float* __restrict__ out) {
    double v = 0.0;
    for (int i = (int)threadIdx.x; i < n; i += 256) v += (double)partials[i];
    __shared__ double sm[256];
    sm[threadIdx.x] = v;
    __syncthreads();
    for (int s = 128; s > 0; s >>= 1) {
        if ((int)threadIdx.x < s) sm[threadIdx.x] += sm[threadIdx.x + s];
        __syncthreads();
    }
    if (threadIdx.x == 0) out[0] = (float)(sm[0] * (1.0 / (double)BATCH));
}

extern "C" void kernel_launch(void* const* d_in, const int* in_sizes, int n_in,
                              void* d_out, int out_size, void* d_ws, size_t ws_size,
                              hipStream_t stream) {
    const float4* pre4 = (const float4*)d_in[0];
    const float4* lab4 = (const float4*)d_in[1];
    float* out = (float*)d_out;
    float* partials = (float*)d_ws;

    int nblk = NBLK;
    if (ws_size < (size_t)nblk * sizeof(float)) {
        nblk = (int)(ws_size / sizeof(float));
        if (nblk < 1) nblk = 1;
    }

    yolo_loss_main<<<nblk, 256, 0, stream>>>(pre4, lab4, partials);
    yolo_loss_final<<<1, 256, 0, stream>>>(partials, nblk, out);
}